// Round 10
// baseline (693.439 us; speedup 1.0000x reference)
//
#include <hip/hip_runtime.h>

#define Bsz 1024
#define Tt  256
#define Vv  32004
#define Dd  50
#define Hh  64
#define RR  32   // vocab rows per build_tables block

typedef _Float16 f16x2 __attribute__((ext_vector_type(2)));
typedef _Float16 f16x8 __attribute__((ext_vector_type(8)));
typedef float    f32x4 __attribute__((ext_vector_type(4)));

// same-wave LDS ordering fence (no barrier, no vmcnt drain)
__device__ __forceinline__ void lds_fence() {
    asm volatile("s_waitcnt lgkmcnt(0)" ::: "memory");
}
__device__ __forceinline__ float fsig(float x) {
    return __fdividef(1.0f, 1.0f + __expf(-x));
}
__device__ __forceinline__ float ftanh(float x) {
    return 2.0f * __fdividef(1.0f, 1.0f + __expf(-2.0f * x)) - 1.0f;
}

// ---------------------------------------------------------------------------
// Prologue: tab[v][g] = sum_d emb[v][d] * Wih[g][d] + bih[g] + bhh[g]
// EXACT round-4 version (best measured ~132 us) — untouched this round.
// ---------------------------------------------------------------------------
__launch_bounds__(256)
__global__ void build_tables(const float* __restrict__ emb,
                             const float* __restrict__ Wih1,
                             const float* __restrict__ bih1,
                             const float* __restrict__ bhh1,
                             const float* __restrict__ Wih2,
                             const float* __restrict__ bih2,
                             const float* __restrict__ bhh2,
                             float* __restrict__ tab1,
                             float* __restrict__ tab2) {
    const int v0 = blockIdx.x * RR;
    const int g  = threadIdx.x;              // gate 0..255
    const int nr = min(RR, Vv - v0);         // rows in this block (tail: 4)

    const float* Wih = blockIdx.y ? Wih2 : Wih1;
    const float* bih = blockIdx.y ? bih2 : bih1;
    const float* bhh = blockIdx.y ? bhh2 : bhh1;
    float*       tab = blockIdx.y ? tab2 : tab1;

    __shared__ __align__(16) float4 wpack[13 * 256];  // 53.2 KB
    __shared__ __align__(16) float  elds[RR * 52];    // 6.66 KB

    {
        const float* wrow = Wih + (size_t)g * Dd;
#pragma unroll
        for (int j = 0; j < 12; ++j) {
            const float2 a = *(const float2*)(wrow + 4 * j);
            const float2 b = *(const float2*)(wrow + 4 * j + 2);
            wpack[j * 256 + g] = make_float4(a.x, a.y, b.x, b.y);
        }
        const float2 t = *(const float2*)(wrow + 48);
        wpack[12 * 256 + g] = make_float4(t.x, t.y, 0.0f, 0.0f);
    }
    for (int i = threadIdx.x; i < nr * 52; i += 256) {
        const int row = i / 52;
        const int col = i - row * 52;
        elds[i] = (col < Dd) ? emb[(size_t)(v0 + row) * Dd + col] : 0.0f;
    }
    __syncthreads();

    const float bias = bih[g] + bhh[g];

    for (int c = 0; c < RR / 8; ++c) {        // 4 chunks of 8 rows
        const int r0 = c * 8;
        float acc[8];
#pragma unroll
        for (int r = 0; r < 8; ++r) acc[r] = 0.0f;

#pragma unroll
        for (int j = 0; j < 13; ++j) {
            const float4 w = wpack[j * 256 + g];
#pragma unroll
            for (int r = 0; r < 8; ++r) {
                const float4 e = *(const float4*)(&elds[(r0 + r) * 52 + 4 * j]);
                acc[r] += e.x * w.x + e.y * w.y + e.z * w.z + e.w * w.w;
            }
        }

#pragma unroll
        for (int r = 0; r < 8; ++r) {
            const int row = r0 + r;
            if (row < nr)
                tab[(size_t)(v0 + row) * 256 + g] = acc[r] + bias;
        }
    }
}

// ---------------------------------------------------------------------------
// Recurrence v6: pure-VALU v_dot2_f32_f16, ONE WAVE per batch row
// (1024 blocks x 64 threads), ZERO barriers, ZERO MFMA.
// Lane gi owns gate rows {gi, 64+gi, 128+gi, 192+gi} = the i/f/g/o of hidden
// unit gi -> gates accumulate and update entirely register-local.
//   - Whh in VGPRs: 4 rows x 32 packed half2 = 128 VGPRs, cvt'd once/phase
//   - h in wave-private LDS as fp16 (128 B): 1 ds_write_b16 + 8 ds_read_b128
//     broadcast per step, lgkm fence only
//   - GEMV = 128 fdot2/step (2 MAC/inst, fp32 accum) vs round-9's 32 MFMAs
//     (16x redundant, 545 cyc) -- per-step issue ~330 cyc
//   - xw fp32 from token table, distance-2 register prefetch (no vmcnt drain)
// ---------------------------------------------------------------------------
__launch_bounds__(64, 1)
__global__ void lstm_main(const int*   __restrict__ s1,
                          const int*   __restrict__ s2,
                          const int*   __restrict__ len1,
                          const int*   __restrict__ len2,
                          const float* __restrict__ tab1,
                          const float* __restrict__ tab2,
                          const float* __restrict__ Whh1,
                          const float* __restrict__ Whh2,
                          const float* __restrict__ Wl1,
                          const float* __restrict__ bl1,
                          const float* __restrict__ Wl2,
                          const float* __restrict__ bl2,
                          float* __restrict__ out) {
    const int lane = threadIdx.x;     // == this lane's hidden unit
    const int b    = blockIdx.x;      // one batch row per block

    __shared__ __align__(16) _Float16 hws[Hh];   // wave-private h (128 B)
    __shared__ int    tokl[Tt];
    __shared__ float  h2s[Hh];
    __shared__ float  ys[128];

    float c = 0.0f, hval = 0.0f, selh = 0.0f, selc = 0.0f;

    for (int phase = 0; phase < 2; ++phase) {
        const float* tab  = phase ? tab2 : tab1;
        const float* Whh  = phase ? Whh2 : Whh1;
        const int*   sent = phase ? s2 : s1;
        const int*   lenp = phase ? len2 : len1;

        // ---- stage this row's tokens (wave-private)
#pragma unroll
        for (int i = 0; i < Tt / 64; ++i)
            tokl[lane + 64 * i] = sent[(size_t)b * Tt + lane + 64 * i];

        // ---- Whh rows for this lane's 4 gates, packed fp16 (once per phase)
        f16x2 wh[4][32];
#pragma unroll
        for (int j = 0; j < 4; ++j) {
            const float* wr = Whh + (size_t)(64 * j + lane) * Hh;
#pragma unroll
            for (int kk = 0; kk < 16; ++kk) {
                const float4 f = *(const float4*)(wr + 4 * kk);
                wh[j][2 * kk]     = f16x2{(_Float16)f.x, (_Float16)f.y};
                wh[j][2 * kk + 1] = f16x2{(_Float16)f.z, (_Float16)f.w};
            }
        }

        const int myidx = lenp[(size_t)b * Hh + lane];

        if (phase) { c = selc; hval = selh; }
        else       { c = 0.0f; hval = 0.0f; }
        selh = 0.0f; selc = 0.0f;
        hws[lane] = (_Float16)hval;
        __syncthreads();          // single wave: cheap; orders tokl + hws

        // ---- xw register prefetch, distance 2
        const float* tabl = tab + lane;
        f32x4 Sa, Sb;
        {
            const int tk0 = tokl[0];
            const float* tr = tabl + (size_t)tk0 * 256;
            Sa[0] = tr[0]; Sa[1] = tr[64]; Sa[2] = tr[128]; Sa[3] = tr[192];
            const int tk1 = tokl[1];
            const float* ts = tabl + (size_t)tk1 * 256;
            Sb[0] = ts[0]; Sb[1] = ts[64]; Sb[2] = ts[128]; Sb[3] = ts[192];
        }

        auto step = [&](int t, f32x4& S) {
            // 8 sub-chains (2 per gate, 16 deep) of v_dot2_f32_f16
            float a0 = S[0], a1 = S[1], a2 = S[2], a3 = S[3];
            float e0 = 0.f,  e1 = 0.f,  e2 = 0.f,  e3 = 0.f;
#pragma unroll
            for (int i = 0; i < 8; ++i) {
                const f16x8 hv = *(const f16x8*)&hws[8 * i];  // broadcast b128
                const f16x2* hp = (const f16x2*)&hv;
#pragma unroll
                for (int pp = 0; pp < 4; ++pp) {
                    const int p = 4 * i + pp;
                    const f16x2 h2 = hp[pp];
                    if (pp & 1) {
                        e0 = __builtin_amdgcn_fdot2(wh[0][p], h2, e0, false);
                        e1 = __builtin_amdgcn_fdot2(wh[1][p], h2, e1, false);
                        e2 = __builtin_amdgcn_fdot2(wh[2][p], h2, e2, false);
                        e3 = __builtin_amdgcn_fdot2(wh[3][p], h2, e3, false);
                    } else {
                        a0 = __builtin_amdgcn_fdot2(wh[0][p], h2, a0, false);
                        a1 = __builtin_amdgcn_fdot2(wh[1][p], h2, a1, false);
                        a2 = __builtin_amdgcn_fdot2(wh[2][p], h2, a2, false);
                        a3 = __builtin_amdgcn_fdot2(wh[3][p], h2, a3, false);
                    }
                }
            }
            const float gI = a0 + e0;
            const float gF = a1 + e1;
            const float gG = a2 + e2;
            const float gO = a3 + e3;

            // refill S for t+2 (no barrier, no vmcnt drain -> loads in flight)
            const int tk = tokl[(t + 2 < Tt) ? t + 2 : Tt - 1];
            const float* tr = tabl + (size_t)tk * 256;
            S[0] = tr[0]; S[1] = tr[64]; S[2] = tr[128]; S[3] = tr[192];

            const float iv = fsig(gI);
            const float fv = fsig(gF);
            const float gv = ftanh(gG);
            const float ov = fsig(gO);
            c = fv * c + iv * gv;
            hval = ov * ftanh(c);
            if (t == myidx) { selh = hval; selc = c; }
            hws[lane] = (_Float16)hval;   // publish h for t+1 (same wave)
            lds_fence();                  // lgkm only
        };

        for (int t = 0; t < Tt; t += 2) {
            step(t,     Sa);
            step(t + 1, Sb);
        }
    }

    // ---------------- epilogue MLP (this row only) --------------------------
    h2s[lane] = selh;
    __syncthreads();
#pragma unroll
    for (int p = 0; p < 2; ++p) {
        const int n = lane + 64 * p;
        float a = bl1[n];
        const float4* wl = (const float4*)(Wl1 + (size_t)n * 64);
#pragma unroll
        for (int k = 0; k < 16; ++k) {
            const float4 wv = wl[k];
            a += h2s[4 * k] * wv.x + h2s[4 * k + 1] * wv.y +
                 h2s[4 * k + 2] * wv.z + h2s[4 * k + 3] * wv.w;
        }
        ys[n] = ftanh(a);
    }
    __syncthreads();
    if (lane < 4) {
        float a = bl2[lane];
        const float* wl = Wl2 + (size_t)lane * 128;
#pragma unroll 8
        for (int k = 0; k < 128; ++k) a += ys[k] * wl[k];
        out[(size_t)b * 4 + lane] = a;
    }
}

// ---------------------------------------------------------------------------
extern "C" void kernel_launch(void* const* d_in, const int* in_sizes, int n_in,
                              void* d_out, int out_size, void* d_ws, size_t ws_size,
                              hipStream_t stream) {
    const int*   s1   = (const int*)d_in[0];
    const int*   s2   = (const int*)d_in[1];
    const int*   l1   = (const int*)d_in[2];
    const int*   l2   = (const int*)d_in[3];
    // d_in[4], d_in[5] (s1_s, s2_s) unused by the reference
    const float* emb  = (const float*)d_in[6];
    const float* Wih1 = (const float*)d_in[7];
    const float* Whh1 = (const float*)d_in[8];
    const float* bih1 = (const float*)d_in[9];
    const float* bhh1 = (const float*)d_in[10];
    const float* Wih2 = (const float*)d_in[11];
    const float* Whh2 = (const float*)d_in[12];
    const float* bih2 = (const float*)d_in[13];
    const float* bhh2 = (const float*)d_in[14];
    const float* Wl1  = (const float*)d_in[15];
    const float* bl1  = (const float*)d_in[16];
    const float* Wl2  = (const float*)d_in[17];
    const float* bl2  = (const float*)d_in[18];
    float* out = (float*)d_out;

    float* tab1 = (float*)d_ws;                       // [V,256] fp32
    float* tab2 = tab1 + (size_t)Vv * 256;            // [V,256] fp32  (65.6 MB)

    dim3 grid((Vv + RR - 1) / RR, 2);
    build_tables<<<grid, 256, 0, stream>>>(emb, Wih1, bih1, bhh1,
                                           Wih2, bih2, bhh2, tab1, tab2);
    lstm_main<<<Bsz, 64, 0, stream>>>(s1, s2, l1, l2, tab1, tab2,
                                      Whh1, Whh2, Wl1, bl1, Wl2, bl2, out);
}